// Round 6
// baseline (206.837 us; speedup 1.0000x reference)
//
#include <hip/hip_runtime.h>
#include <hip/hip_bf16.h>

// Attention_65541200937161: B=16, N=1024, E=512, H=8, DH=64
// Round 6: attention gets double-buffered K/V staging (stage t+1 issued before
// compute of t, single barrier per tile -> global->LDS latency hidden), d
// prefetched one tile ahead, exp2-folded softmax. GEMMs unchanged (round 3/5).

#define Bc  16
#define Nc  1024
#define Ec  512
#define Hc  8
#define DHc 64

typedef float  f32x4  __attribute__((ext_vector_type(4)));
typedef short  s16x4  __attribute__((ext_vector_type(4)));
typedef short  s16x8  __attribute__((ext_vector_type(8)));
typedef __bf16 bf16x8 __attribute__((ext_vector_type(8)));

static __device__ __forceinline__ f32x4 mfma16(s16x8 a, s16x8 b, f32x4 c) {
    return __builtin_amdgcn_mfma_f32_16x16x32_bf16(
        __builtin_bit_cast(bf16x8, a), __builtin_bit_cast(bf16x8, b), c, 0, 0, 0);
}

static __device__ __forceinline__ unsigned short f2bf(float f) {
    return __builtin_bit_cast(unsigned short, __float2bfloat16(f));
}

static __device__ __forceinline__ s16x8 pack_bf16(f32x4 a, f32x4 b) {
    s16x8 r;
    r[0] = (short)f2bf(a[0]); r[1] = (short)f2bf(a[1]);
    r[2] = (short)f2bf(a[2]); r[3] = (short)f2bf(a[3]);
    r[4] = (short)f2bf(b[0]); r[5] = (short)f2bf(b[1]);
    r[6] = (short)f2bf(b[2]); r[7] = (short)f2bf(b[3]);
    return r;
}

// async global->LDS, 16B per lane; LDS dest = wave-uniform base + lane*16.
static __device__ __forceinline__ void gld16(const void* g, void* l) {
    __builtin_amdgcn_global_load_lds(
        (const __attribute__((address_space(1))) void*)g,
        (__attribute__((address_space(3))) void*)l, 16, 0, 0);
}

// ---------------- projection / output GEMMs (unchanged from round 3) --------
template<int MODE, bool ABF16>
__global__ __launch_bounds__(256) void gemm_bt(
    const void* __restrict__ Ap, const float* __restrict__ Wm,
    const float* __restrict__ bias, void* __restrict__ outp)
{
    __shared__ float Bs[128 * 32];
    __shared__ float As_raw[128 * 32];
    unsigned short* Asb = (unsigned short*)As_raw;

    const int tid = threadIdx.x;
    const int w = tid >> 6, lane = tid & 63;
    const int lr = lane & 15, grp = lane >> 4;
    const int wr = w >> 1, wc = w & 1;
    const int m0 = blockIdx.x * 128, n0 = blockIdx.y * 128;

    f32x4 acc[4][4];
#pragma unroll
    for (int i = 0; i < 4; ++i)
#pragma unroll
        for (int j = 0; j < 4; ++j) acc[i][j] = (f32x4)(0.0f);

    const int h8 = lane >> 3, l8 = lane & 7;
    const int fcol = ((l8 ^ h8) << 2);
    const int h4 = lane >> 2, l4 = lane & 3;
    const int bcol = ((l4 ^ (h4 & 3)) << 3);
    const int o0 = (((grp << 1) ^ (lr & 7)) << 2);
    const int ob = ((grp ^ (lr & 3)) << 3);

    const float* Af = (const float*)Ap;
    const unsigned short* Ab = (const unsigned short*)Ap;

    for (int k0 = 0; k0 < Ec; k0 += 32) {
        __syncthreads();
#pragma unroll
        for (int i = 0; i < 4; ++i) {
            const int chunk = i * 4 + w;
            const int row = chunk * 8 + h8;
            gld16(Wm + (size_t)(n0 + row) * Ec + k0 + fcol,
                  (char*)Bs + chunk * 1024 + lane * 16);
        }
        if constexpr (!ABF16) {
#pragma unroll
            for (int i = 0; i < 4; ++i) {
                const int chunk = i * 4 + w;
                const int row = chunk * 8 + h8;
                gld16(Af + (size_t)(m0 + row) * Ec + k0 + fcol,
                      (char*)As_raw + chunk * 1024 + lane * 16);
            }
        } else {
#pragma unroll
            for (int i = 0; i < 2; ++i) {
                const int chunk = i * 4 + w;
                const int row = chunk * 16 + h4;
                gld16(Ab + (size_t)(m0 + row) * Ec + k0 + bcol,
                      (char*)As_raw + chunk * 1024 + lane * 16);
            }
        }
        __syncthreads();

        s16x8 afr[4], bfr[4];
#pragma unroll
        for (int mi = 0; mi < 4; ++mi) {
            const int row = wr * 64 + mi * 16 + lr;
            if constexpr (!ABF16) {
                const float* p = As_raw + row * 32;
                afr[mi] = pack_bf16(*(const f32x4*)(p + o0), *(const f32x4*)(p + (o0 ^ 4)));
            } else {
                afr[mi] = *(const s16x8*)(Asb + row * 32 + ob);
            }
        }
#pragma unroll
        for (int ni = 0; ni < 4; ++ni) {
            const int row = wc * 64 + ni * 16 + lr;
            const float* p = Bs + row * 32;
            bfr[ni] = pack_bf16(*(const f32x4*)(p + o0), *(const f32x4*)(p + (o0 ^ 4)));
        }
#pragma unroll
        for (int mi = 0; mi < 4; ++mi)
#pragma unroll
            for (int ni = 0; ni < 4; ++ni)
                acc[mi][ni] = mfma16(afr[mi], bfr[ni], acc[mi][ni]);
    }

#pragma unroll
    for (int mi = 0; mi < 4; ++mi) {
        const int mbase = m0 + wr * 64 + mi * 16 + grp * 4;
#pragma unroll
        for (int ni = 0; ni < 4; ++ni) {
            const int f = n0 + wc * 64 + ni * 16 + lr;
            const float bi = bias[f];
            f32x4 vv = acc[mi][ni];
            if constexpr (MODE == 2) {
                float* out = (float*)outp;
#pragma unroll
                for (int r = 0; r < 4; ++r)
                    out[(size_t)(mbase + r) * Ec + f] = vv[r] + bi;
            } else if constexpr (MODE == 0) {
                unsigned short* out = (unsigned short*)outp;
                const int hh = f >> 6, dh = f & 63;
#pragma unroll
                for (int r = 0; r < 4; ++r) {
                    const int m = mbase + r;
                    out[(((size_t)(m >> 10) * Hc + hh) * Nc + (m & (Nc - 1))) * DHc + dh] =
                        f2bf(vv[r] + bi);
                }
            } else {
                unsigned short* out = (unsigned short*)outp;
                const int hh = f >> 6, dh = f & 63;
                const int bb = mbase >> 10, n = mbase & (Nc - 1);
                s16x4 pk;
#pragma unroll
                for (int r = 0; r < 4; ++r) pk[r] = (short)f2bf(vv[r] + bi);
                *(s16x4*)&out[(((size_t)bb * Hc + hh) * DHc + dh) * Nc + n] = pk;
            }
        }
    }
}

// ---------------- attention v4: double-buffered K/V --------------------------
// Loop shape (T3 minimum-2-phase): barrier(top) -> issue stage(t+1) into the
// other buffer + prefetch d(t+1) -> compute tile t. The barrier's implicit
// vmcnt(0) drain happens AFTER ~1 tile of compute, so stage latency is hidden.
__global__ __launch_bounds__(256) void attn_kernel(
    const unsigned short* __restrict__ qh, const unsigned short* __restrict__ kh,
    const unsigned short* __restrict__ vt, const float* __restrict__ dmat,
    unsigned short* __restrict__ xh)
{
    __shared__ unsigned short K_lds[2][64 * 64];  // 2 x 8 KB
    __shared__ unsigned short V_lds[2][64 * 64];  // 2 x 8 KB
    __shared__ unsigned short P_lds[4][16][72];   // 9 KB

    const int w = threadIdx.x >> 6, lane = threadIdx.x & 63;
    const int lr = lane & 15, grp = lane >> 4;
    const int h8 = lane >> 3, l8 = lane & 7;
    const int q0 = blockIdx.x * 64;
    const int h = blockIdx.y, b = blockIdx.z;
    const int bh = b * Hc + h;
    const int qw = q0 + w * 16;
    const int kofs = grp * 4;
    const int scol = (l8 ^ h8) * 8;                    // staging src col (bf16 elems)
    const float* dbase = dmat + ((size_t)b * Nc + qw + lr) * Nc;

    const float LOG2E  = 1.4426950408889634f;
    const float SC     = 0.125f * LOG2E;               // logit scale in log2 space
    const float MC     = -4.0f * LOG2E;                // fixed-max shift in log2 space

    // Q fragment (B operand of swapped QK): Q[qw+lr][ks*32+grp*8 ..+8]
    s16x8 bq[2];
#pragma unroll
    for (int ks = 0; ks < 2; ++ks)
        bq[ks] = *reinterpret_cast<const s16x8*>(
            qh + ((size_t)bh * Nc + qw + lr) * DHc + ks * 32 + grp * 8);

    f32x4 acc[4];
#pragma unroll
    for (int c = 0; c < 4; ++c) acc[c] = (f32x4)(0.0f);
    float lsum = 0.f;

    auto stage = [&](int buf, int kt) {
#pragma unroll
        for (int i = 0; i < 2; ++i) {
            const int ch = w * 2 + i;                  // 8 chunks of 1KB over 4 waves
            gld16(kh + ((size_t)bh * Nc + kt * 64 + ch * 8 + h8) * DHc + scol,
                  (char*)K_lds[buf] + ch * 1024 + lane * 16);
            gld16(vt + ((size_t)bh * DHc + ch * 8 + h8) * Nc + kt * 64 + scol,
                  (char*)V_lds[buf] + ch * 1024 + lane * 16);
        }
    };

    f32x4 dv_cur[4], dv_nxt[4];
    stage(0, 0);
#pragma unroll
    for (int c = 0; c < 4; ++c)
        dv_cur[c] = *reinterpret_cast<const f32x4*>(dbase + c * 16 + kofs);

    const int NT = Nc / 64;
    for (int kt = 0; kt < NT; ++kt) {
        const int cur = kt & 1;
        __syncthreads();   // drains each wave's stage of tile kt; publishes buf[cur]
        if (kt + 1 < NT) {
            stage(cur ^ 1, kt + 1);
#pragma unroll
            for (int c = 0; c < 4; ++c)
                dv_nxt[c] = *reinterpret_cast<const f32x4*>(
                    dbase + (kt + 1) * 64 + c * 16 + kofs);
        }

        // QK^T swapped: lgt[c][r] = logit(k = kt*64+c*16+grp*4+r, q = qw+lr)
        f32x4 lgt[4];
#pragma unroll
        for (int c = 0; c < 4; ++c) lgt[c] = (f32x4)(0.0f);
#pragma unroll
        for (int ks = 0; ks < 2; ++ks) {
#pragma unroll
            for (int c = 0; c < 4; ++c) {
                const int row = c * 16 + lr;
                const int slot = (4 * ks + grp) ^ (lr & 7);
                s16x8 ak = *reinterpret_cast<const s16x8*>(
                    (const char*)K_lds[cur] + row * 128 + slot * 16);
                lgt[c] = mfma16(ak, bq[ks], lgt[c]);
            }
        }
        // softmax (fixed max 4, exp2-folded) + P*d -> LDS [q=lr][k]
#pragma unroll
        for (int c = 0; c < 4; ++c) {
            s16x4 pk;
#pragma unroll
            for (int r = 0; r < 4; ++r) {
                const float dl = fmaf(dv_cur[c][r], LOG2E, MC);   // lgt-independent
                const float p = __builtin_amdgcn_exp2f(fmaf(lgt[c][r], SC, dl));
                lsum += p;
                pk[r] = (short)f2bf(p * dv_cur[c][r]);
            }
            *reinterpret_cast<s16x4*>(&P_lds[w][lr][c * 16 + kofs]) = pk;
        }
        // PV: A = P (rows=q), B = V^T (cols=dh) from LDS
#pragma unroll
        for (int ks = 0; ks < 2; ++ks) {
            s16x8 pa = *reinterpret_cast<const s16x8*>(&P_lds[w][lr][ks * 32 + grp * 8]);
#pragma unroll
            for (int c = 0; c < 4; ++c) {
                const int row = c * 16 + lr;
                const int slot = (4 * ks + grp) ^ (lr & 7);
                s16x8 bv = *reinterpret_cast<const s16x8*>(
                    (const char*)V_lds[cur] + row * 128 + slot * 16);
                acc[c] = mfma16(pa, bv, acc[c]);
            }
        }
#pragma unroll
        for (int c = 0; c < 4; ++c) dv_cur[c] = dv_nxt[c];
    }
    // full denominator for q = qw+lr, then redistribute to PV output rows.
    lsum += __shfl_xor(lsum, 16, 64);
    lsum += __shfl_xor(lsum, 32, 64);
    const float invd = 1.0f / lsum;
    float inv[4];
#pragma unroll
    for (int r = 0; r < 4; ++r) inv[r] = __shfl(invd, grp * 4 + r, 64);
#pragma unroll
    for (int c = 0; c < 4; ++c)
#pragma unroll
        for (int r = 0; r < 4; ++r)
            xh[((size_t)b * Nc + qw + grp * 4 + r) * Ec + h * DHc + c * 16 + lr] =
                f2bf(acc[c][r] * inv[r]);
}

extern "C" void kernel_launch(void* const* d_in, const int* in_sizes, int n_in,
                              void* d_out, int out_size, void* d_ws, size_t ws_size,
                              hipStream_t stream)
{
    (void)in_sizes; (void)n_in; (void)out_size; (void)ws_size;
    const float* q  = (const float*)d_in[0];
    const float* k  = (const float*)d_in[1];
    const float* v  = (const float*)d_in[2];
    const float* dm = (const float*)d_in[3];
    const float* Wq = (const float*)d_in[4];
    const float* bq = (const float*)d_in[5];
    const float* Wk = (const float*)d_in[6];
    const float* bk = (const float*)d_in[7];
    const float* Wv = (const float*)d_in[8];
    const float* bv = (const float*)d_in[9];
    const float* Wp = (const float*)d_in[10];
    const float* bp = (const float*)d_in[11];
    float* out = (float*)d_out;

    const size_t sz = (size_t)Bc * Hc * Nc * DHc;   // 8,388,608 elements
    unsigned short* qhb = (unsigned short*)d_ws;
    unsigned short* khb = qhb + sz;
    unsigned short* vtb = khb + sz;
    unsigned short* xhb = vtb + sz;

    dim3 blk(256);
    dim3 gg(Bc * Nc / 128, Ec / 128);               // 128 x 4
    gemm_bt<0, false><<<gg, blk, 0, stream>>>(q, Wq, bq, qhb);
    gemm_bt<0, false><<<gg, blk, 0, stream>>>(k, Wk, bk, khb);
    gemm_bt<1, false><<<gg, blk, 0, stream>>>(v, Wv, bv, vtb);
    attn_kernel<<<dim3(Nc / 64, Hc, Bc), blk, 0, stream>>>(qhb, khb, vtb, dm, xhb);
    gemm_bt<2, true><<<gg, blk, 0, stream>>>(xhb, Wp, bp, out);
}

// Round 7
// 180.764 us; speedup vs baseline: 1.1442x; 1.1442x over previous
//
#include <hip/hip_runtime.h>
#include <hip/hip_bf16.h>

// Attention_65541200937161: B=16, N=1024, E=512, H=8, DH=64
// Round 7: revert dbuf (occupancy > pipelining). Attention: 8 waves / 128
// q-rows per block (32 waves/CU), single-buffer K/V, XCD-aware block decode.
// q/k/v projections fused into one dispatch. exp2-folded fixed-max softmax.

#define Bc  16
#define Nc  1024
#define Ec  512
#define Hc  8
#define DHc 64

typedef float  f32x4  __attribute__((ext_vector_type(4)));
typedef short  s16x4  __attribute__((ext_vector_type(4)));
typedef short  s16x8  __attribute__((ext_vector_type(8)));
typedef __bf16 bf16x8 __attribute__((ext_vector_type(8)));

static __device__ __forceinline__ f32x4 mfma16(s16x8 a, s16x8 b, f32x4 c) {
    return __builtin_amdgcn_mfma_f32_16x16x32_bf16(
        __builtin_bit_cast(bf16x8, a), __builtin_bit_cast(bf16x8, b), c, 0, 0, 0);
}

static __device__ __forceinline__ unsigned short f2bf(float f) {
    return __builtin_bit_cast(unsigned short, __float2bfloat16(f));
}

static __device__ __forceinline__ s16x8 pack_bf16(f32x4 a, f32x4 b) {
    s16x8 r;
    r[0] = (short)f2bf(a[0]); r[1] = (short)f2bf(a[1]);
    r[2] = (short)f2bf(a[2]); r[3] = (short)f2bf(a[3]);
    r[4] = (short)f2bf(b[0]); r[5] = (short)f2bf(b[1]);
    r[6] = (short)f2bf(b[2]); r[7] = (short)f2bf(b[3]);
    return r;
}

// async global->LDS, 16B per lane; LDS dest = wave-uniform base + lane*16.
static __device__ __forceinline__ void gld16(const void* g, void* l) {
    __builtin_amdgcn_global_load_lds(
        (const __attribute__((address_space(1))) void*)g,
        (__attribute__((address_space(3))) void*)l, 16, 0, 0);
}

// ---------------- fused q/k/v projection (blockIdx.z selects tensor) --------
// Y[m,f] = sum_e X[m,e]*W[f,e] + b[f]; 128x128 tile, BK=32, f32 LDS staging
// with both-sides XOR swizzle. mode 0 (q,k): head-major bf16; mode 1 (v):
// per-head transposed bf16.
__global__ __launch_bounds__(256) void proj3_kernel(
    const float* __restrict__ qi, const float* __restrict__ ki,
    const float* __restrict__ vi,
    const float* __restrict__ Wq, const float* __restrict__ Wk,
    const float* __restrict__ Wv,
    const float* __restrict__ bq, const float* __restrict__ bk,
    const float* __restrict__ bv,
    unsigned short* __restrict__ qo, unsigned short* __restrict__ ko,
    unsigned short* __restrict__ vo)
{
    const int z = blockIdx.z;
    const float* Af   = z == 0 ? qi : (z == 1 ? ki : vi);
    const float* Wm   = z == 0 ? Wq : (z == 1 ? Wk : Wv);
    const float* bias = z == 0 ? bq : (z == 1 ? bk : bv);
    unsigned short* out = z == 0 ? qo : (z == 1 ? ko : vo);
    const int mode = (z == 2) ? 1 : 0;

    __shared__ float Bs[128 * 32];
    __shared__ float As_raw[128 * 32];

    const int tid = threadIdx.x;
    const int w = tid >> 6, lane = tid & 63;
    const int lr = lane & 15, grp = lane >> 4;
    const int wr = w >> 1, wc = w & 1;
    const int m0 = blockIdx.x * 128, n0 = blockIdx.y * 128;

    f32x4 acc[4][4];
#pragma unroll
    for (int i = 0; i < 4; ++i)
#pragma unroll
        for (int j = 0; j < 4; ++j) acc[i][j] = (f32x4)(0.0f);

    const int h8 = lane >> 3, l8 = lane & 7;
    const int fcol = ((l8 ^ h8) << 2);
    const int o0 = (((grp << 1) ^ (lr & 7)) << 2);

    for (int k0 = 0; k0 < Ec; k0 += 32) {
        __syncthreads();
#pragma unroll
        for (int i = 0; i < 4; ++i) {
            const int chunk = i * 4 + w;
            const int row = chunk * 8 + h8;
            gld16(Wm + (size_t)(n0 + row) * Ec + k0 + fcol,
                  (char*)Bs + chunk * 1024 + lane * 16);
            gld16(Af + (size_t)(m0 + row) * Ec + k0 + fcol,
                  (char*)As_raw + chunk * 1024 + lane * 16);
        }
        __syncthreads();

        s16x8 afr[4], bfr[4];
#pragma unroll
        for (int mi = 0; mi < 4; ++mi) {
            const float* p = As_raw + (wr * 64 + mi * 16 + lr) * 32;
            afr[mi] = pack_bf16(*(const f32x4*)(p + o0), *(const f32x4*)(p + (o0 ^ 4)));
        }
#pragma unroll
        for (int ni = 0; ni < 4; ++ni) {
            const float* p = Bs + (wc * 64 + ni * 16 + lr) * 32;
            bfr[ni] = pack_bf16(*(const f32x4*)(p + o0), *(const f32x4*)(p + (o0 ^ 4)));
        }
#pragma unroll
        for (int mi = 0; mi < 4; ++mi)
#pragma unroll
            for (int ni = 0; ni < 4; ++ni)
                acc[mi][ni] = mfma16(afr[mi], bfr[ni], acc[mi][ni]);
    }

#pragma unroll
    for (int mi = 0; mi < 4; ++mi) {
        const int mbase = m0 + wr * 64 + mi * 16 + grp * 4;
#pragma unroll
        for (int ni = 0; ni < 4; ++ni) {
            const int f = n0 + wc * 64 + ni * 16 + lr;
            const float bi = bias[f];
            f32x4 vv = acc[mi][ni];
            const int hh = f >> 6, dh = f & 63;
            if (mode == 0) {
#pragma unroll
                for (int r = 0; r < 4; ++r) {
                    const int m = mbase + r;
                    out[(((size_t)(m >> 10) * Hc + hh) * Nc + (m & (Nc - 1))) * DHc + dh] =
                        f2bf(vv[r] + bi);
                }
            } else {
                const int bb = mbase >> 10, n = mbase & (Nc - 1);
                s16x4 pk;
#pragma unroll
                for (int r = 0; r < 4; ++r) pk[r] = (short)f2bf(vv[r] + bi);
                *(s16x4*)&out[(((size_t)bb * Hc + hh) * DHc + dh) * Nc + n] = pk;
            }
        }
    }
}

// ---------------- output projection (bf16 A, f32 out) ------------------------
__global__ __launch_bounds__(256) void outproj_kernel(
    const unsigned short* __restrict__ Ab, const float* __restrict__ Wm,
    const float* __restrict__ bias, float* __restrict__ out)
{
    __shared__ float Bs[128 * 32];
    __shared__ unsigned short Asb[128 * 32];   // bf16 tile, 8 KB

    const int tid = threadIdx.x;
    const int w = tid >> 6, lane = tid & 63;
    const int lr = lane & 15, grp = lane >> 4;
    const int wr = w >> 1, wc = w & 1;
    const int m0 = blockIdx.x * 128, n0 = blockIdx.y * 128;

    f32x4 acc[4][4];
#pragma unroll
    for (int i = 0; i < 4; ++i)
#pragma unroll
        for (int j = 0; j < 4; ++j) acc[i][j] = (f32x4)(0.0f);

    const int h8 = lane >> 3, l8 = lane & 7;
    const int fcol = ((l8 ^ h8) << 2);
    const int h4 = lane >> 2, l4 = lane & 3;
    const int bcol = ((l4 ^ (h4 & 3)) << 3);
    const int o0 = (((grp << 1) ^ (lr & 7)) << 2);
    const int ob = ((grp ^ (lr & 3)) << 3);

    for (int k0 = 0; k0 < Ec; k0 += 32) {
        __syncthreads();
#pragma unroll
        for (int i = 0; i < 4; ++i) {
            const int chunk = i * 4 + w;
            const int row = chunk * 8 + h8;
            gld16(Wm + (size_t)(n0 + row) * Ec + k0 + fcol,
                  (char*)Bs + chunk * 1024 + lane * 16);
        }
#pragma unroll
        for (int i = 0; i < 2; ++i) {
            const int chunk = i * 4 + w;
            const int row = chunk * 16 + h4;
            gld16(Ab + (size_t)(m0 + row) * Ec + k0 + bcol,
                  (char*)Asb + chunk * 1024 + lane * 16);
        }
        __syncthreads();

        s16x8 afr[4], bfr[4];
#pragma unroll
        for (int mi = 0; mi < 4; ++mi)
            afr[mi] = *(const s16x8*)(Asb + (wr * 64 + mi * 16 + lr) * 32 + ob);
#pragma unroll
        for (int ni = 0; ni < 4; ++ni) {
            const float* p = Bs + (wc * 64 + ni * 16 + lr) * 32;
            bfr[ni] = pack_bf16(*(const f32x4*)(p + o0), *(const f32x4*)(p + (o0 ^ 4)));
        }
#pragma unroll
        for (int mi = 0; mi < 4; ++mi)
#pragma unroll
            for (int ni = 0; ni < 4; ++ni)
                acc[mi][ni] = mfma16(afr[mi], bfr[ni], acc[mi][ni]);
    }

#pragma unroll
    for (int mi = 0; mi < 4; ++mi) {
        const int mbase = m0 + wr * 64 + mi * 16 + grp * 4;
#pragma unroll
        for (int ni = 0; ni < 4; ++ni) {
            const int f = n0 + wc * 64 + ni * 16 + lr;
            const float bi = bias[f];
            f32x4 vv = acc[mi][ni];
#pragma unroll
            for (int r = 0; r < 4; ++r)
                out[(size_t)(mbase + r) * Ec + f] = vv[r] + bi;
        }
    }
}

// ---------------- attention v5: 8 waves, 128 q-rows, single-buffer ----------
// 32 waves/CU (4 blocks x 8 waves). K/V tile staged once per block per k-step,
// serves 128 q-rows. XCD-aware decode: each XCD owns 2 b-values (K/V+d L2
// locality). Swapped QK^T; fixed-max exp2 softmax; P via LDS round-trip.
__global__ __launch_bounds__(512) void attn_kernel(
    const unsigned short* __restrict__ qh, const unsigned short* __restrict__ kh,
    const unsigned short* __restrict__ vt, const float* __restrict__ dmat,
    unsigned short* __restrict__ xh)
{
    __shared__ unsigned short K_lds[64 * 64];     // 8 KB
    __shared__ unsigned short V_lds[64 * 64];     // 8 KB
    __shared__ unsigned short P_lds[8][16][72];   // 18 KB

    // XCD-aware decode: 1024 blocks, xcd = lin%8 -> give each XCD contiguous
    // (qt,h) x 2 consecutive b. swz = x + 8*(h + 8*b) ordering.
    const int lin = blockIdx.x;
    const int swz = ((lin & 7) << 7) | (lin >> 3);
    const int qt = swz & 7, h = (swz >> 3) & 7, b = swz >> 6;

    const int tid = threadIdx.x;
    const int w = tid >> 6, lane = tid & 63;
    const int lr = lane & 15, grp = lane >> 4;
    const int h8 = lane >> 3, l8 = lane & 7;
    const int q0 = qt * 128;
    const int bh = b * Hc + h;
    const int qw = q0 + w * 16;
    const int kofs = grp * 4;
    const int scol = (l8 ^ h8) * 8;                    // staging src col (bf16)
    const float* dbase = dmat + ((size_t)b * Nc + qw + lr) * Nc;

    const float LOG2E = 1.4426950408889634f;
    const float SC    = 0.125f * LOG2E;
    const float MC    = -4.0f * LOG2E;

    s16x8 bq[2];
#pragma unroll
    for (int ks = 0; ks < 2; ++ks)
        bq[ks] = *reinterpret_cast<const s16x8*>(
            qh + ((size_t)bh * Nc + qw + lr) * DHc + ks * 32 + grp * 8);

    f32x4 acc[4];
#pragma unroll
    for (int c = 0; c < 4; ++c) acc[c] = (f32x4)(0.0f);
    float lsum = 0.f;

    for (int kt = 0; kt < Nc / 64; ++kt) {
        const int k0 = kt * 64;
        __syncthreads();                               // prev tile reads done
        // stage K/V: 8 chunks of 1KB each over 8 waves (1 K + 1 V per wave)
        gld16(kh + ((size_t)bh * Nc + k0 + w * 8 + h8) * DHc + scol,
              (char*)K_lds + w * 1024 + lane * 16);
        gld16(vt + ((size_t)bh * DHc + w * 8 + h8) * Nc + k0 + scol,
              (char*)V_lds + w * 1024 + lane * 16);
        // d loads overlap the staging drain
        f32x4 dv[4];
#pragma unroll
        for (int c = 0; c < 4; ++c)
            dv[c] = *reinterpret_cast<const f32x4*>(dbase + k0 + c * 16 + kofs);
        __syncthreads();                               // staging visible

        // QK^T swapped: lgt[c][r] = logit(k = k0+c*16+grp*4+r, q = qw+lr)
        f32x4 lgt[4];
#pragma unroll
        for (int c = 0; c < 4; ++c) lgt[c] = (f32x4)(0.0f);
#pragma unroll
        for (int ks = 0; ks < 2; ++ks) {
#pragma unroll
            for (int c = 0; c < 4; ++c) {
                const int row = c * 16 + lr;
                const int slot = (4 * ks + grp) ^ (lr & 7);
                s16x8 ak = *reinterpret_cast<const s16x8*>(
                    (const char*)K_lds + row * 128 + slot * 16);
                lgt[c] = mfma16(ak, bq[ks], lgt[c]);
            }
        }
        // softmax (fixed max 4, exp2) + P*d -> LDS [q=lr][k]
#pragma unroll
        for (int c = 0; c < 4; ++c) {
            s16x4 pk;
#pragma unroll
            for (int r = 0; r < 4; ++r) {
                const float dl = fmaf(dv[c][r], LOG2E, MC);
                const float p = __builtin_amdgcn_exp2f(fmaf(lgt[c][r], SC, dl));
                lsum += p;
                pk[r] = (short)f2bf(p * dv[c][r]);
            }
            *reinterpret_cast<s16x4*>(&P_lds[w][lr][c * 16 + kofs]) = pk;
        }
        // PV
#pragma unroll
        for (int ks = 0; ks < 2; ++ks) {
            s16x8 pa = *reinterpret_cast<const s16x8*>(&P_lds[w][lr][ks * 32 + grp * 8]);
#pragma unroll
            for (int c = 0; c < 4; ++c) {
                const int row = c * 16 + lr;
                const int slot = (4 * ks + grp) ^ (lr & 7);
                s16x8 bv = *reinterpret_cast<const s16x8*>(
                    (const char*)V_lds + row * 128 + slot * 16);
                acc[c] = mfma16(pa, bv, acc[c]);
            }
        }
    }
    lsum += __shfl_xor(lsum, 16, 64);
    lsum += __shfl_xor(lsum, 32, 64);
    const float invd = 1.0f / lsum;
    float inv[4];
#pragma unroll
    for (int r = 0; r < 4; ++r) inv[r] = __shfl(invd, grp * 4 + r, 64);
#pragma unroll
    for (int c = 0; c < 4; ++c)
#pragma unroll
        for (int r = 0; r < 4; ++r)
            xh[((size_t)b * Nc + qw + grp * 4 + r) * Ec + h * DHc + c * 16 + lr] =
                f2bf(acc[c][r] * inv[r]);
}

extern "C" void kernel_launch(void* const* d_in, const int* in_sizes, int n_in,
                              void* d_out, int out_size, void* d_ws, size_t ws_size,
                              hipStream_t stream)
{
    (void)in_sizes; (void)n_in; (void)out_size; (void)ws_size;
    const float* q  = (const float*)d_in[0];
    const float* k  = (const float*)d_in[1];
    const float* v  = (const float*)d_in[2];
    const float* dm = (const float*)d_in[3];
    const float* Wq = (const float*)d_in[4];
    const float* bq = (const float*)d_in[5];
    const float* Wk = (const float*)d_in[6];
    const float* bk = (const float*)d_in[7];
    const float* Wv = (const float*)d_in[8];
    const float* bv = (const float*)d_in[9];
    const float* Wp = (const float*)d_in[10];
    const float* bp = (const float*)d_in[11];
    float* out = (float*)d_out;

    const size_t sz = (size_t)Bc * Hc * Nc * DHc;   // 8,388,608 elements
    unsigned short* qhb = (unsigned short*)d_ws;
    unsigned short* khb = qhb + sz;
    unsigned short* vtb = khb + sz;
    unsigned short* xhb = vtb + sz;

    proj3_kernel<<<dim3(Bc * Nc / 128, Ec / 128, 3), dim3(256), 0, stream>>>(
        q, k, v, Wq, Wk, Wv, bq, bk, bv, qhb, khb, vtb);
    attn_kernel<<<dim3(Bc * Hc * Nc / 128), dim3(512), 0, stream>>>(
        qhb, khb, vtb, dm, xhb);
    outproj_kernel<<<dim3(Bc * Nc / 128, Ec / 128), dim3(256), 0, stream>>>(
        xhb, Wp, bp, out);
}